// Round 1
// baseline (451.176 us; speedup 1.0000x reference)
//
#include <hip/hip_runtime.h>
#include <hip/hip_bf16.h>

// CustomTransformerBlock: B=4,S=2048,D=1024,H=16,DH=64,W=1024,DFF=4096
#define BB 4
#define SS 2048
#define DD 1024
#define HH 16
#define DHH 64
#define WW 1024
#define DFF 4096
#define MM (BB*SS)
#define NEGV (-1e10f)

using f32x4 = __attribute__((ext_vector_type(4))) float;
using s16x8 = __attribute__((ext_vector_type(8))) short;
using s16x4 = __attribute__((ext_vector_type(4))) short;

typedef const __attribute__((address_space(1))) void* gas_t;
typedef __attribute__((address_space(3))) void* las_t;

__device__ inline short f2b(float f) {
  __hip_bfloat16 h = __float2bfloat16(f);
  return __builtin_bit_cast(short, h);
}
__device__ inline float b2f(short u) {
  __hip_bfloat16 h = __builtin_bit_cast(__hip_bfloat16, u);
  return __bfloat162float(h);
}

// 16B global->LDS direct. LDS dest is wave-uniform base + lane*16 (HW rule).
__device__ inline void gload_lds16(const short* g, short* lds) {
  __builtin_amdgcn_global_load_lds((gas_t)g, (las_t)lds, 16, 0, 0);
}

__device__ inline f32x4 mfma16(s16x8 a, s16x8 b, f32x4 c) {
  return __builtin_amdgcn_mfma_f32_16x16x32_bf16(a, b, c, 0, 0, 0);
}

// -------------------- LayerNorm (row of 1024), out bf16 --------------------
template<int IN_BF16>
__global__ __launch_bounds__(256) void ln_kernel(const void* __restrict__ inp,
                                                 const float* __restrict__ g,
                                                 const float* __restrict__ bta,
                                                 short* __restrict__ outp) {
  int row = blockIdx.x;
  int t = threadIdx.x;
  float v[4];
  if constexpr (IN_BF16) {
    s16x4 r4 = *((const s16x4*)((const short*)inp + (size_t)row*DD) + t);
    v[0]=b2f(r4[0]); v[1]=b2f(r4[1]); v[2]=b2f(r4[2]); v[3]=b2f(r4[3]);
  } else {
    f32x4 r4 = *((const f32x4*)((const float*)inp + (size_t)row*DD) + t);
    v[0]=r4[0]; v[1]=r4[1]; v[2]=r4[2]; v[3]=r4[3];
  }
  float s = v[0]+v[1]+v[2]+v[3];
  float sq = v[0]*v[0]+v[1]*v[1]+v[2]*v[2]+v[3]*v[3];
  for (int m=1;m<64;m<<=1){ s += __shfl_xor(s,m); sq += __shfl_xor(sq,m); }
  __shared__ float red[8];
  int wv = t>>6;
  if ((t&63)==0){ red[wv]=s; red[4+wv]=sq; }
  __syncthreads();
  s  = red[0]+red[1]+red[2]+red[3];
  sq = red[4]+red[5]+red[6]+red[7];
  float mean = s*(1.f/DD);
  float rstd = rsqrtf(sq*(1.f/DD) - mean*mean + 1e-5f);
  int col = t*4;
  s16x4 o;
  #pragma unroll
  for (int j=0;j<4;++j) o[j] = f2b((v[j]-mean)*rstd*g[col+j]+bta[col+j]);
  *((s16x4*)(outp + (size_t)row*DD) + t) = o;
}

// ------------- fp32 [K][N] -> bf16 [N][K] transpose-cast (weights) ----------
__global__ __launch_bounds__(256) void transpose_cast(const float* __restrict__ in,
                                                      short* __restrict__ out,
                                                      int K, int N) {
  __shared__ float tile[32][33];
  int n0 = blockIdx.x*32, k0 = blockIdx.y*32;
  int tx = threadIdx.x & 31, ty = threadIdx.x >> 5;
  #pragma unroll
  for (int j=0;j<4;++j) tile[ty+8*j][tx] = in[(size_t)(k0+ty+8*j)*N + n0+tx];
  __syncthreads();
  #pragma unroll
  for (int j=0;j<4;++j) out[(size_t)(n0+ty+8*j)*K + k0+tx] = f2b(tile[tx][ty+8*j]);
}

// -------------------- GEMM: C = A[M,K] * Bt[N,K]^T + bias --------------------
// 128x128 tile, BK=32, 256 thr = 4 waves (2x2), each wave 64x64 via 4x4 16x16x32.
// LDS tiles [128][32] with XOR swizzle cslot ^= (row>>1)&3 so ds_read_b128 is 2-way.
// EPI: 0=q(bf16 out), 1=kv(split k/v panels), 2=ff1(silu,bf16), 3=ff2(+x, f32 out)
template<int EPI>
__global__ __launch_bounds__(256) void gemm_bt(const short* __restrict__ A,
                                               const short* __restrict__ Bt,
                                               const float* __restrict__ bias,
                                               void* __restrict__ out1,
                                               void* __restrict__ out2,
                                               const float* __restrict__ resid,
                                               int N, int K) {
  __shared__ short As[128*32], Bs[128*32];
  int tid = threadIdx.x, l = tid&63;
  int wv = tid>>6, wm = wv>>1, wn = wv&1;
  int bx = blockIdx.x, by = blockIdx.y;
  const short* Ablk;
  if constexpr (EPI==1) {
    int b_ = (by*128)>>10;          // batch
    int w0 = (by*128)&1023;         // window row
    Ablk = A + ((size_t)b_*SS + (SS-WW) + w0)*DD;
  } else {
    Ablk = A + (size_t)by*128*K;
  }
  const short* Bblk = Bt + (size_t)bx*128*K;
  f32x4 acc[4][4];
  #pragma unroll
  for (int i=0;i<4;++i)
    #pragma unroll
    for(int j=0;j<4;++j)
      #pragma unroll
      for(int r=0;r<4;++r) acc[i][j][r]=0.f;
  int rA = l & 15;
  int cslot = (((l>>4) ^ ((l>>1)&3))*8);
  for (int kt=0; kt<K; kt+=32) {
    __syncthreads();
    #pragma unroll
    for (int p=0;p<2;++p) {
      int s = p*256 + tid;
      int srow = s>>2;
      int scs = (((s&3) ^ ((s>>3)&3))*8);   // pre-swizzled source slot
      gload_lds16(Ablk + (size_t)srow*K + kt + scs, &As[(p*256 + (tid & ~63))*8]);
      gload_lds16(Bblk + (size_t)srow*K + kt + scs, &Bs[(p*256 + (tid & ~63))*8]);
    }
    __syncthreads();
    s16x8 af[4], bfr[4];
    #pragma unroll
    for (int mf=0;mf<4;++mf) af[mf]  = *(const s16x8*)&As[(wm*64+mf*16+rA)*32 + cslot];
    #pragma unroll
    for (int nf=0;nf<4;++nf) bfr[nf] = *(const s16x8*)&Bs[(wn*64+nf*16+rA)*32 + cslot];
    #pragma unroll
    for (int mf=0;mf<4;++mf)
      #pragma unroll
      for (int nf=0;nf<4;++nf)
        acc[mf][nf] = mfma16(af[mf], bfr[nf], acc[mf][nf]);
  }
  #pragma unroll
  for (int mf=0;mf<4;++mf) {
    #pragma unroll
    for (int nf=0;nf<4;++nf) {
      #pragma unroll
      for (int r=0;r<4;++r) {
        int row = by*128 + wm*64 + mf*16 + ((l>>4)<<2) + r;  // C row=(l>>4)*4+r
        int col = bx*128 + wn*64 + nf*16 + (l&15);           // C col=l&15
        float v = acc[mf][nf][r] + bias[col];
        if constexpr (EPI==0) {
          ((short*)out1)[(size_t)row*N + col] = f2b(v);
        } else if constexpr (EPI==1) {
          int b_ = row>>10, w_ = row&1023;
          if (col < DD) {        // K head: [b][h][w][dh]
            int h = col>>6, dh = col&63;
            ((short*)out1)[(((size_t)(b_*HH+h))*WW + w_)*DHH + dh] = f2b(v);
          } else {               // V head transposed: [b][h][dh][w]
            int cc = col - DD;
            int h = cc>>6, dh = cc&63;
            ((short*)out2)[(((size_t)(b_*HH+h))*DHH + dh)*WW + w_] = f2b(v);
          }
        } else if constexpr (EPI==2) {
          float sv = v / (1.f + __expf(-v));   // silu
          ((short*)out1)[(size_t)row*N + col] = f2b(sv);
        } else {
          ((float*)out1)[(size_t)row*N + col] = v + resid[(size_t)row*N + col];
        }
      }
    }
  }
}

// -------------------- Flash attention over W=1024 keys --------------------
// grid (S/64, H, B); 4 waves, each owns 16 q-rows; 64-key chunks.
__global__ __launch_bounds__(256) void attn_kernel(const short* __restrict__ q,
    const short* __restrict__ kpan, const short* __restrict__ vtpan,
    const int* __restrict__ pad, short* __restrict__ outp) {
  __shared__ short Ks[64*64], Vts[64*64];
  __shared__ short P[4][16*72];   // wave-private P, 144B row stride
  int tid = threadIdx.x, l = tid&63, wv = tid>>6;
  int qt = blockIdx.x, h = blockIdx.y, bb = blockIdx.z;
  int s0 = qt*64;
  int srow0 = s0 + wv*16;
  const short* qbase = q + ((size_t)bb*SS + srow0 + (l&15))*DD + h*DHH + ((l>>4)*8);
  s16x8 aq0 = *(const s16x8*)qbase;
  s16x8 aq1 = *(const s16x8*)(qbase + 32);
  const short* kbase = kpan + (size_t)(bb*HH+h)*WW*DHH;
  const short* vbase = vtpan + (size_t)(bb*HH+h)*DHH*WW;
  const int* padb = pad + bb*SS + (SS-WW);
  f32x4 oacc[4];
  #pragma unroll
  for (int i=0;i<4;++i)
    #pragma unroll
    for (int r=0;r<4;++r) oacc[i][r]=0.f;
  float mrun[4], lrun[4];
  #pragma unroll
  for (int r=0;r<4;++r){ mrun[r]=-INFINITY; lrun[r]=0.f; }
  int nch = (qt+1 < 16) ? qt+1 : 16;

  auto body = [&](int c) {
    __syncthreads();   // previous chunk's LDS reads done
    #pragma unroll
    for (int p=0;p<2;++p) {
      int s = p*256 + tid;
      int row = s>>3;
      int scs = (((s&7) ^ (row&7))*8);
      gload_lds16(kbase + (size_t)(c*64+row)*DHH + scs, &Ks[(p*256 + (tid&~63))*8]);
      gload_lds16(vbase + (size_t)row*WW + c*64 + scs,  &Vts[(p*256 + (tid&~63))*8]);
    }
    __syncthreads();   // staging visible (vmcnt drained by barrier)
    // scores: S = Q * K^T (16 q-rows x 64 keys), K as Bt (key-major, dh-contig)
    f32x4 sc[4];
    #pragma unroll
    for (int nf=0;nf<4;++nf)
      #pragma unroll
      for (int r=0;r<4;++r) sc[nf][r]=0.f;
    #pragma unroll
    for (int nf=0;nf<4;++nf) {
      int row = nf*16 + (l&15);
      s16x8 bk0 = *(const s16x8*)&Ks[row*64 + ((((l>>4)    ) ^ (l&7))*8)];
      s16x8 bk1 = *(const s16x8*)&Ks[row*64 + (((4 + (l>>4)) ^ (l&7))*8)];
      sc[nf] = mfma16(aq0, bk0, sc[nf]);
      sc[nf] = mfma16(aq1, bk1, sc[nf]);
    }
    // mask + online softmax (rows live in 16-lane groups; shfl_xor 1,2,4,8)
    float vals[4][4];
    float pm[4] = {-INFINITY,-INFINITY,-INFINITY,-INFINITY};
    #pragma unroll
    for (int nf=0;nf<4;++nf) {
      int j = c*64 + nf*16 + (l&15);
      int pd = padb[j];
      #pragma unroll
      for (int r=0;r<4;++r) {
        int sq_ = srow0 + ((l>>4)<<2) + r;
        float xv = (pd || (j > sq_)) ? NEGV : sc[nf][r]*0.03125f; // 1/sqrt(1024)
        vals[nf][r] = xv;
        pm[r] = fmaxf(pm[r], xv);
      }
    }
    #pragma unroll
    for (int m=1;m<16;m<<=1)
      #pragma unroll
      for (int r=0;r<4;++r) pm[r] = fmaxf(pm[r], __shfl_xor(pm[r], m));
    float scale[4], ls[4];
    #pragma unroll
    for (int r=0;r<4;++r) {
      float mn = fmaxf(mrun[r], pm[r]);
      scale[r] = __expf(mrun[r]-mn);
      mrun[r] = mn;
      ls[r] = 0.f;
    }
    #pragma unroll
    for (int nf=0;nf<4;++nf)
      #pragma unroll
      for (int r=0;r<4;++r) {
        float p_ = __expf(vals[nf][r]-mrun[r]);
        vals[nf][r]=p_; ls[r]+=p_;
      }
    #pragma unroll
    for (int m=1;m<16;m<<=1)
      #pragma unroll
      for (int r=0;r<4;++r) ls[r] += __shfl_xor(ls[r], m);
    #pragma unroll
    for (int r=0;r<4;++r) lrun[r] = lrun[r]*scale[r] + ls[r];
    #pragma unroll
    for (int nf=0;nf<4;++nf)
      #pragma unroll
      for (int r=0;r<4;++r) oacc[nf][r] *= scale[r];
    // P -> wave-private LDS (bf16), then PV MFMA
    short* Pw = &P[wv][0];
    #pragma unroll
    for (int nf=0;nf<4;++nf)
      #pragma unroll
      for (int r=0;r<4;++r)
        Pw[(((l>>4)<<2)+r)*72 + nf*16 + (l&15)] = f2b(vals[nf][r]);
    #pragma unroll
    for (int ks=0;ks<2;++ks) {
      s16x8 ap = *(const s16x8*)&Pw[(l&15)*72 + ks*32 + ((l>>4)*8)];
      #pragma unroll
      for (int nf=0;nf<4;++nf) {
        int row = nf*16 + (l&15);
        s16x8 bv = *(const s16x8*)&Vts[row*64 + (((ks*4 + (l>>4)) ^ (l&7))*8)];
        oacc[nf] = mfma16(ap, bv, oacc[nf]);
      }
    }
  };

  for (int c=0;c<nch;++c) body(c);
  // exact all-masked fallback: reference softmaxes uniformly over ALL 1024 keys
  // when every visible key is padded -> must process the causally-dead chunks too.
  int dead = 0;
  #pragma unroll
  for (int r=0;r<4;++r) dead |= (mrun[r] < -5e9f) ? 1 : 0;
  if (__syncthreads_or(dead)) {
    for (int c=nch;c<16;++c) body(c);
  }
  #pragma unroll
  for (int nf=0;nf<4;++nf)
    #pragma unroll
    for (int r=0;r<4;++r) {
      int srow = srow0 + ((l>>4)<<2) + r;
      float o = oacc[nf][r] / lrun[r];
      outp[((size_t)bb*SS + srow)*DD + h*DHH + nf*16 + (l&15)] = f2b(o);
    }
}

// -------------------- driver --------------------
extern "C" void kernel_launch(void* const* d_in, const int* in_sizes, int n_in,
                              void* d_out, int out_size, void* d_ws, size_t ws_size,
                              hipStream_t stream) {
  const float* x    = (const float*)d_in[0];
  const int*   pad  = (const int*)d_in[1];   // bool mask, assuming int32 on device
  const float* ln1g = (const float*)d_in[2];
  const float* ln1b = (const float*)d_in[3];
  const float* wq   = (const float*)d_in[4];
  const float* bq   = (const float*)d_in[5];
  const float* wkv  = (const float*)d_in[6];
  const float* bkv  = (const float*)d_in[7];
  const float* ln2g = (const float*)d_in[8];
  const float* ln2b = (const float*)d_in[9];
  const float* w1   = (const float*)d_in[10];
  const float* b1   = (const float*)d_in[11];
  const float* w2   = (const float*)d_in[12];
  const float* b2   = (const float*)d_in[13];

  char* ws = (char*)d_ws;
  const size_t MB = 1024*1024;
  short* ln1x = (short*)(ws + 0);        // 16MB, dead after KV gemm
  short* qb   = (short*)(ws + 16*MB);    // 16MB, dead after attn
  short* kpan = (short*)(ws + 32*MB);    //  8MB, dead after attn
  short* vtp  = (short*)(ws + 40*MB);    //  8MB, dead after attn
  short* h1   = (short*)(ws + 0);        // 64MB, reuses [0,64MB)
  short* outb = (short*)(ws + 64*MB);    // 16MB attn out
  short* hb   = (short*)(ws + 80*MB);    // 16MB ln2 out
  short* wqT  = (short*)(ws + 96*MB);    //  2MB
  short* wkvT = (short*)(ws + 98*MB);    //  4MB
  short* w1T  = (short*)(ws + 102*MB);   //  8MB
  short* w2T  = (short*)(ws + 110*MB);   //  8MB  (total 118MB)

  transpose_cast<<<dim3(32,32),  256,0,stream>>>(wq,  wqT,  1024, 1024);
  transpose_cast<<<dim3(64,32),  256,0,stream>>>(wkv, wkvT, 1024, 2048);
  transpose_cast<<<dim3(128,32), 256,0,stream>>>(w1,  w1T,  1024, 4096);
  transpose_cast<<<dim3(32,128), 256,0,stream>>>(w2,  w2T,  4096, 1024);
  ln_kernel<0><<<MM,256,0,stream>>>(x, ln1g, ln1b, ln1x);
  gemm_bt<0><<<dim3(8,64), 256,0,stream>>>(ln1x, wqT,  bq,  qb,   nullptr, nullptr, 1024, 1024);
  gemm_bt<1><<<dim3(16,32),256,0,stream>>>(ln1x, wkvT, bkv, kpan, vtp,     nullptr, 2048, 1024);
  attn_kernel<<<dim3(32,16,4),256,0,stream>>>(qb, kpan, vtp, pad, outb);
  ln_kernel<1><<<MM,256,0,stream>>>(outb, ln2g, ln2b, hb);
  gemm_bt<2><<<dim3(32,64),256,0,stream>>>(hb, w1T, b1, h1,    nullptr, nullptr, 4096, 1024);
  gemm_bt<3><<<dim3(8,64), 256,0,stream>>>(h1, w2T, b2, d_out, nullptr, x,       1024, 4096);
}